// Round 2
// baseline (6375.466 us; speedup 1.0000x reference)
//
#include <hip/hip_runtime.h>

#define DI __device__ __forceinline__

using half8 = __attribute__((ext_vector_type(8))) _Float16;
using f32x4 = __attribute__((ext_vector_type(4))) float;

static constexpr int T_ = 256;
static constexpr int B_ = 32;
static constexpr int H_ = 1024;
static constexpr int V_ = 8192;
static constexpr int GBLK = 256;   // 128 layer-0 blocks + 128 layer-1 blocks
static constexpr int TPB = 256;    // 4 waves
static constexpr int JPB = 8;      // hidden dims per block
static constexpr int BH = B_ * H_;
static constexpr int NCTR = 8;     // split barrier counters (contention)

// Static device scratch: no d_ws dependence, no hipMalloc.
__device__ _Float16 g_y0[(T_ + 1) * BH];   // layer-0 h chain; slot s = h after s steps
__device__ _Float16 g_y1[(T_ + 1) * BH];   // layer-1 h chain
__device__ unsigned g_cnt[NCTR * 32];      // 128B-strided counters

__global__ void init_bar_k() {
  if (threadIdx.x < NCTR) g_cnt[threadIdx.x * 32] = 0u;
}

DI void grid_barrier(unsigned round) {
  __syncthreads();
  if (threadIdx.x == 0) {
    __threadfence();  // release: flush this block's global writes (device scope)
    __hip_atomic_fetch_add(&g_cnt[(blockIdx.x & (NCTR - 1)) * 32], 1u,
                           __ATOMIC_RELAXED, __HIP_MEMORY_SCOPE_AGENT);
    const unsigned tgt = (GBLK / NCTR) * round;  // 32 arrivals per counter per round
    for (;;) {
      bool ok = true;
#pragma unroll
      for (int i = 0; i < NCTR; ++i)
        ok &= (__hip_atomic_load(&g_cnt[i * 32], __ATOMIC_RELAXED,
                                 __HIP_MEMORY_SCOPE_AGENT) >= tgt);
      if (ok) break;
      __builtin_amdgcn_s_sleep(2);
    }
    __threadfence();  // acquire: invalidate stale L1/L2 before reading peers' h
  }
  __syncthreads();
}

DI float sigmf(float v) { return 1.0f / (1.0f + __expf(-v)); }
DI float tanhf_(float v) { return 1.0f - 2.0f / (__expf(2.0f * v) + 1.0f); }

DI half8 load8_cvt(const float* __restrict__ p) {
  const float4* q = (const float4*)p;
  float4 a = q[0], b = q[1];
  half8 r;
  r[0] = (_Float16)a.x; r[1] = (_Float16)a.y; r[2] = (_Float16)a.z; r[3] = (_Float16)a.w;
  r[4] = (_Float16)b.x; r[5] = (_Float16)b.y; r[6] = (_Float16)b.z; r[7] = (_Float16)b.w;
  return r;
}

// Fused 2-layer persistent LSTM. blocks 0-127: layer 0 (step s).
// blocks 128-255: layer 1 (step s-1, software pipeline).
__global__ __launch_bounds__(TPB, 1) void lstm_fused(
    const float* __restrict__ Wih0,  // (4096, 8192)
    const float* __restrict__ Whh0,  // (4096, 1024)
    const float* __restrict__ bih0, const float* __restrict__ bhh0,
    const float* __restrict__ Wih1,  // (4096, 1024)
    const float* __restrict__ Whh1,  // (4096, 1024)
    const float* __restrict__ bih1, const float* __restrict__ bhh1,
    const int* __restrict__ x,       // (256, 32)
    const float* __restrict__ Hst,   // (2, 32, 1024)
    const float* __restrict__ Cst,   // (2, 32, 1024)
    float* __restrict__ y1out,       // (256, 32, 1024)
    float* __restrict__ outh,        // (2, 32, 1024)
    float* __restrict__ outc)        // (2, 32, 1024)
{
  const int tid = threadIdx.x;
  const int bid = blockIdx.x;
  const int layer = bid >> 7;
  const int kb = bid & 127;
  const int jbase = kb * JPB;
  const int lane = tid & 63;
  const int w = tid >> 6;
  const int m = w & 1;        // M-half (batch 0-15 / 16-31)
  const int n = w >> 1;       // N-half (gate rows 0-15 / 16-31)
  const int bb = tid >> 3;    // batch index (activation phase)
  const int jj = tid & 7;     // local hidden dim
  const int j = jbase + jj;

  __shared__ float gates_lds[32 * 36];

  const float* Whh = layer ? Whh1 : Whh0;
  const float* bih = layer ? bih1 : bih0;
  const float* bhh = layer ? bhh1 : bhh0;
  _Float16* mych = layer ? g_y1 : g_y0;

  // init h chain slot 0 + c registers
  mych[bb * H_ + j] = (_Float16)Hst[layer * BH + bb * H_ + j];
  float c_reg = Cst[layer * BH + bb * H_ + j];
  float bsum[4];
#pragma unroll
  for (int g = 0; g < 4; ++g) bsum[g] = bih[g * H_ + j] + bhh[g * H_ + j];

  // B-fragment geometry: lane holds W[gate-row][k0..k0+7]
  const int rowl = lane & 15;
  const int gW = n * 2 + (rowl >> 3);
  const int jW = rowl & 7;
  const int RW = gW * H_ + jbase + jW;
  const int kgrp = (lane >> 4) * 8;
  const int arow = m * 16 + (lane & 15);   // batch row this lane feeds to MFMA A

  half8 wf[32];   // W_hh fragments (persistent, VGPRs)
#pragma unroll
  for (int kk = 0; kk < 32; ++kk)
    wf[kk] = load8_cvt(Whh + (size_t)RW * H_ + kk * 32 + kgrp);

  half8 wi[32];   // layer 1 only: W_ih1 fragments (same geometry)
  if (layer) {
#pragma unroll
    for (int kk = 0; kk < 32; ++kk)
      wi[kk] = load8_cvt(Wih1 + (size_t)RW * H_ + kk * 32 + kgrp);
  }

  grid_barrier(1);   // h(0) slices visible everywhere

  float h_last = 0.0f;
  for (int s = 0; s <= T_; ++s) {
    if (layer == 0) {
      if (s < T_) {
        const int t = s;
        const int xv = x[t * B_ + bb];
        const float gx0 = Wih0[(size_t)(0 * H_ + j) * V_ + xv];
        const float gx1 = Wih0[(size_t)(1 * H_ + j) * V_ + xv];
        const float gx2 = Wih0[(size_t)(2 * H_ + j) * V_ + xv];
        const float gx3 = Wih0[(size_t)(3 * H_ + j) * V_ + xv];

        const _Float16* hsrc = g_y0 + (size_t)s * BH;
        const half8* ap = (const half8*)(hsrc + arow * H_ + kgrp);
        f32x4 acc0 = {0.f, 0.f, 0.f, 0.f}, acc1 = {0.f, 0.f, 0.f, 0.f};
#pragma unroll
        for (int kk = 0; kk < 32; kk += 2) {
          acc0 = __builtin_amdgcn_mfma_f32_16x16x32_f16(ap[kk * 4], wf[kk], acc0, 0, 0, 0);
          acc1 = __builtin_amdgcn_mfma_f32_16x16x32_f16(ap[(kk + 1) * 4], wf[kk + 1], acc1, 0, 0, 0);
        }
        acc0 = acc0 + acc1;

        const int gb = m * 16 + (lane >> 4) * 4;
        const int gc = n * 16 + (lane & 15);
#pragma unroll
        for (int r = 0; r < 4; ++r) gates_lds[(gb + r) * 36 + gc] = acc0[r];
        __syncthreads();

        const float gi = gates_lds[bb * 36 + 0 + jj] + gx0 + bsum[0];
        const float gf = gates_lds[bb * 36 + 8 + jj] + gx1 + bsum[1];
        const float gg = gates_lds[bb * 36 + 16 + jj] + gx2 + bsum[2];
        const float go = gates_lds[bb * 36 + 24 + jj] + gx3 + bsum[3];
        const float iv = sigmf(gi), fv = sigmf(gf), gv = tanhf_(gg), ov = sigmf(go);
        c_reg = fv * c_reg + iv * gv;
        const float hv = ov * tanhf_(c_reg);
        h_last = hv;
        g_y0[(size_t)(s + 1) * BH + bb * H_ + j] = (_Float16)hv;
      }
    } else {
      if (s >= 1) {
        const int t = s - 1;
        const _Float16* hsrc = g_y1 + (size_t)(s - 1) * BH;   // h1(t-1)
        const _Float16* ysrc = g_y0 + (size_t)s * BH;         // y0[t]
        const half8* ap  = (const half8*)(hsrc + arow * H_ + kgrp);
        const half8* ayp = (const half8*)(ysrc + arow * H_ + kgrp);
        f32x4 acc0 = {0.f, 0.f, 0.f, 0.f}, acc1 = {0.f, 0.f, 0.f, 0.f};
#pragma unroll
        for (int kk = 0; kk < 32; ++kk) {
          acc0 = __builtin_amdgcn_mfma_f32_16x16x32_f16(ap[kk * 4], wf[kk], acc0, 0, 0, 0);
          acc1 = __builtin_amdgcn_mfma_f32_16x16x32_f16(ayp[kk * 4], wi[kk], acc1, 0, 0, 0);
        }
        acc0 = acc0 + acc1;

        const int gb = m * 16 + (lane >> 4) * 4;
        const int gc = n * 16 + (lane & 15);
#pragma unroll
        for (int r = 0; r < 4; ++r) gates_lds[(gb + r) * 36 + gc] = acc0[r];
        __syncthreads();

        const float gi = gates_lds[bb * 36 + 0 + jj] + bsum[0];
        const float gf = gates_lds[bb * 36 + 8 + jj] + bsum[1];
        const float gg = gates_lds[bb * 36 + 16 + jj] + bsum[2];
        const float go = gates_lds[bb * 36 + 24 + jj] + bsum[3];
        const float iv = sigmf(gi), fv = sigmf(gf), gv = tanhf_(gg), ov = sigmf(go);
        c_reg = fv * c_reg + iv * gv;
        const float hv = ov * tanhf_(c_reg);
        h_last = hv;
        g_y1[(size_t)s * BH + bb * H_ + j] = (_Float16)hv;
        y1out[(size_t)t * BH + bb * H_ + j] = hv;
      }
    }
    grid_barrier((unsigned)s + 2);
  }

  outh[layer * BH + bb * H_ + j] = h_last;
  outc[layer * BH + bb * H_ + j] = c_reg;
}

// ---------------------------------------------------------------------------
extern "C" void kernel_launch(void* const* d_in, const int* in_sizes, int n_in,
                              void* d_out, int out_size, void* d_ws, size_t ws_size,
                              hipStream_t stream) {
  (void)in_sizes; (void)n_in; (void)d_ws; (void)ws_size; (void)out_size;

  const int*   x    = (const int*)  d_in[0];
  const float* Hst  = (const float*)d_in[1];
  const float* Cst  = (const float*)d_in[2];
  const float* Wih0 = (const float*)d_in[3];
  const float* Whh0 = (const float*)d_in[4];
  const float* bih0 = (const float*)d_in[5];
  const float* bhh0 = (const float*)d_in[6];
  const float* Wih1 = (const float*)d_in[7];
  const float* Whh1 = (const float*)d_in[8];
  const float* bih1 = (const float*)d_in[9];
  const float* bhh1 = (const float*)d_in[10];

  float* out   = (float*)d_out;
  float* y1out = out;                                   // (256,32,1024)
  float* outh  = out + (size_t)T_ * BH;                 // (2,32,1024)
  float* outc  = outh + (size_t)2 * BH;                 // (2,32,1024)

  hipLaunchKernelGGL(init_bar_k, dim3(1), dim3(64), 0, stream);
  hipLaunchKernelGGL(lstm_fused, dim3(GBLK), dim3(TPB), 0, stream,
                     Wih0, Whh0, bih0, bhh0, Wih1, Whh1, bih1, bhh1,
                     x, Hst, Cst, y1out, outh, outc);
}

// Round 3
// 4474.961 us; speedup vs baseline: 1.4247x; 1.4247x over previous
//
#include <hip/hip_runtime.h>

#define DI __device__ __forceinline__

using half8 = __attribute__((ext_vector_type(8))) _Float16;
using f32x4 = __attribute__((ext_vector_type(4))) float;

static constexpr int T_ = 256;
static constexpr int B_ = 32;
static constexpr int H_ = 1024;
static constexpr int V_ = 8192;
static constexpr int GBLK = 256;   // 128 layer-0 blocks + 128 layer-1 blocks
static constexpr int TPB = 256;    // 4 waves
static constexpr int JPB = 8;      // hidden dims per block
static constexpr int BH = B_ * H_;
static constexpr int NCTR = 8;     // split barrier counters

// Static device scratch (no d_ws dependence).
__device__ _Float16 g_y0[(T_ + 1) * BH];    // layer-0 h chain; slot s = h after s steps
__device__ _Float16 g_y1[(T_ + 1) * BH];    // layer-1 h chain
__device__ _Float16 g_Wt[(size_t)V_ * 4096]; // W_ih0 transposed, fp16: [vocab][4H]
__device__ unsigned g_cnt[NCTR * 32];        // 128B-strided counters

__global__ void init_bar_k() {
  if (threadIdx.x < NCTR) g_cnt[threadIdx.x * 32] = 0u;
}

// ---------------------------------------------------------------------------
// Prepass: W_ih0 (4096 x 8192) f32  ->  g_Wt (8192 x 4096) fp16, LDS-tiled.
// ---------------------------------------------------------------------------
__global__ __launch_bounds__(256) void transpose_wih0(const float* __restrict__ in) {
  __shared__ _Float16 t[64][72];   // [v][r], +8 halfs pad
  const int bc = blockIdx.x & 127;        // 128 vocab tiles
  const int br = blockIdx.x >> 7;         // 64 row tiles
  const int r0 = br * 64, v0 = bc * 64;
  const int tx = threadIdx.x & 15, ty = threadIdx.x >> 4;
#pragma unroll
  for (int it = 0; it < 4; ++it) {
    const int row = ty + it * 16;
    const float4 f = *(const float4*)&in[(size_t)(r0 + row) * V_ + v0 + tx * 4];
    t[tx * 4 + 0][row] = (_Float16)f.x;
    t[tx * 4 + 1][row] = (_Float16)f.y;
    t[tx * 4 + 2][row] = (_Float16)f.z;
    t[tx * 4 + 3][row] = (_Float16)f.w;
  }
  __syncthreads();
#pragma unroll
  for (int it = 0; it < 4; ++it) {
    const int vrow = ty + it * 16;
    union { _Float16 h[4]; unsigned long long u; } o;
    o.h[0] = t[vrow][tx * 4 + 0]; o.h[1] = t[vrow][tx * 4 + 1];
    o.h[2] = t[vrow][tx * 4 + 2]; o.h[3] = t[vrow][tx * 4 + 3];
    *(unsigned long long*)&g_Wt[(size_t)(v0 + vrow) * 4096 + r0 + tx * 4] = o.u;
  }
}

// ---------------------------------------------------------------------------
// Device-coherent data movement (sc1 path via agent-scope atomics; no fences)
// ---------------------------------------------------------------------------
DI half8 ld_h16_agent(const _Float16* p) {
  union { unsigned long long u[2]; half8 v; } r;
  r.u[0] = __hip_atomic_load((const unsigned long long*)p, __ATOMIC_RELAXED,
                             __HIP_MEMORY_SCOPE_AGENT);
  r.u[1] = __hip_atomic_load((const unsigned long long*)p + 1, __ATOMIC_RELAXED,
                             __HIP_MEMORY_SCOPE_AGENT);
  return r.v;
}

DI void st_h_agent(_Float16* p, float v) {
  const _Float16 h = (_Float16)v;
  __hip_atomic_store((short*)p, __builtin_bit_cast(short, h), __ATOMIC_RELAXED,
                     __HIP_MEMORY_SCOPE_AGENT);
}

DI void grid_barrier(unsigned round) {
  __syncthreads();   // drains each wave's vmem (h-stores reach LLC) + block sync
  if (threadIdx.x == 0) {
    __hip_atomic_fetch_add(&g_cnt[(blockIdx.x & (NCTR - 1)) * 32], 1u,
                           __ATOMIC_RELAXED, __HIP_MEMORY_SCOPE_AGENT);
    const unsigned tgt = (GBLK / NCTR) * round;
    for (;;) {
      bool ok = true;
#pragma unroll
      for (int i = 0; i < NCTR; ++i)
        ok &= (__hip_atomic_load(&g_cnt[i * 32], __ATOMIC_RELAXED,
                                 __HIP_MEMORY_SCOPE_AGENT) >= tgt);
      if (ok) break;
      __builtin_amdgcn_s_sleep(2);
    }
  }
  __syncthreads();
}

DI float sigmf(float v) { return 1.0f / (1.0f + __expf(-v)); }
DI float tanhf_(float v) { return 1.0f - 2.0f / (__expf(2.0f * v) + 1.0f); }

DI half8 load8_cvt(const float* __restrict__ p) {
  const float4* q = (const float4*)p;
  float4 a = q[0], b = q[1];
  half8 r;
  r[0] = (_Float16)a.x; r[1] = (_Float16)a.y; r[2] = (_Float16)a.z; r[3] = (_Float16)a.w;
  r[4] = (_Float16)b.x; r[5] = (_Float16)b.y; r[6] = (_Float16)b.z; r[7] = (_Float16)b.w;
  return r;
}

// Fused 2-layer persistent LSTM. blocks 0-127: layer 0 (step s);
// blocks 128-255: layer 1 (step s-1).
__global__ __launch_bounds__(TPB, 1) void lstm_fused(
    const float* __restrict__ Whh0,
    const float* __restrict__ bih0, const float* __restrict__ bhh0,
    const float* __restrict__ Wih1,
    const float* __restrict__ Whh1,
    const float* __restrict__ bih1, const float* __restrict__ bhh1,
    const int* __restrict__ x,
    const float* __restrict__ Hst,
    const float* __restrict__ Cst,
    float* __restrict__ y1out,
    float* __restrict__ outh,
    float* __restrict__ outc)
{
  const int tid = threadIdx.x;
  const int bid = blockIdx.x;
  const int layer = bid >> 7;
  const int kb = bid & 127;
  const int jbase = kb * JPB;
  const int lane = tid & 63;
  const int w = tid >> 6;
  const int m = w & 1;        // M-half (batch 0-15 / 16-31)
  const int n = w >> 1;       // N-half (gate rows 0-15 / 16-31)
  const int bb = tid >> 3;    // batch index (activation phase)
  const int jj = tid & 7;     // local hidden dim
  const int j = jbase + jj;

  __shared__ float gates_lds[32 * 36];

  const float* Whh = layer ? Whh1 : Whh0;
  const float* bih = layer ? bih1 : bih0;
  const float* bhh = layer ? bhh1 : bhh0;
  _Float16* mych = layer ? g_y1 : g_y0;

  // init h chain slot 0 (device-coherent) + c registers
  st_h_agent(&mych[bb * H_ + j], Hst[layer * BH + bb * H_ + j]);
  float c_reg = Cst[layer * BH + bb * H_ + j];
  float bsum[4];
#pragma unroll
  for (int g = 0; g < 4; ++g) bsum[g] = bih[g * H_ + j] + bhh[g * H_ + j];

  // B-fragment geometry
  const int rowl = lane & 15;
  const int gW = n * 2 + (rowl >> 3);
  const int jW = rowl & 7;
  const int RW = gW * H_ + jbase + jW;
  const int kgrp = (lane >> 4) * 8;
  const int arow = m * 16 + (lane & 15);

  half8 wf[32];   // W_hh fragments (persistent in regs)
#pragma unroll
  for (int kk = 0; kk < 32; ++kk)
    wf[kk] = load8_cvt(Whh + (size_t)RW * H_ + kk * 32 + kgrp);

  half8 wi[32];   // layer 1: W_ih1 fragments
  if (layer) {
#pragma unroll
    for (int kk = 0; kk < 32; ++kk)
      wi[kk] = load8_cvt(Wih1 + (size_t)RW * H_ + kk * 32 + kgrp);
  }

  grid_barrier(1);

  float h_last = 0.0f;
  for (int s = 0; s <= T_; ++s) {
    if (layer == 0) {
      if (s < T_) {
        // input-side gates: coalesced fp16 gather from transposed table
        const int xv = x[s * B_ + bb];
        const _Float16* gb_ = g_Wt + (size_t)xv * 4096 + j;
        const float gx0 = (float)gb_[0];
        const float gx1 = (float)gb_[1024];
        const float gx2 = (float)gb_[2048];
        const float gx3 = (float)gb_[3072];

        const _Float16* hsrc = g_y0 + (size_t)s * BH + arow * H_ + kgrp;
        f32x4 acc0 = {0.f, 0.f, 0.f, 0.f}, acc1 = {0.f, 0.f, 0.f, 0.f};
        half8 a[32];
#pragma unroll
        for (int kk = 0; kk < 32; ++kk) a[kk] = ld_h16_agent(hsrc + kk * 32);
#pragma unroll
        for (int kk = 0; kk < 32; kk += 2) {
          acc0 = __builtin_amdgcn_mfma_f32_16x16x32_f16(a[kk], wf[kk], acc0, 0, 0, 0);
          acc1 = __builtin_amdgcn_mfma_f32_16x16x32_f16(a[kk + 1], wf[kk + 1], acc1, 0, 0, 0);
        }
        acc0 = acc0 + acc1;

        const int gb = m * 16 + (lane >> 4) * 4;
        const int gc = n * 16 + (lane & 15);
#pragma unroll
        for (int r = 0; r < 4; ++r) gates_lds[(gb + r) * 36 + gc] = acc0[r];
        __syncthreads();

        const float gi = gates_lds[bb * 36 + 0 + jj] + gx0 + bsum[0];
        const float gf = gates_lds[bb * 36 + 8 + jj] + gx1 + bsum[1];
        const float gg = gates_lds[bb * 36 + 16 + jj] + gx2 + bsum[2];
        const float go = gates_lds[bb * 36 + 24 + jj] + gx3 + bsum[3];
        const float iv = sigmf(gi), fv = sigmf(gf), gv = tanhf_(gg), ov = sigmf(go);
        c_reg = fv * c_reg + iv * gv;
        const float hv = ov * tanhf_(c_reg);
        h_last = hv;
        st_h_agent(&g_y0[(size_t)(s + 1) * BH + bb * H_ + j], hv);
      }
    } else {
      if (s >= 1) {
        const _Float16* hsrc = g_y1 + (size_t)(s - 1) * BH + arow * H_ + kgrp;
        const _Float16* ysrc = g_y0 + (size_t)s * BH + arow * H_ + kgrp;
        f32x4 acc0 = {0.f, 0.f, 0.f, 0.f}, acc1 = {0.f, 0.f, 0.f, 0.f};
        half8 a[32], ay[32];
#pragma unroll
        for (int kk = 0; kk < 32; ++kk) a[kk] = ld_h16_agent(hsrc + kk * 32);
#pragma unroll
        for (int kk = 0; kk < 32; ++kk) ay[kk] = ld_h16_agent(ysrc + kk * 32);
#pragma unroll
        for (int kk = 0; kk < 32; ++kk) {
          acc0 = __builtin_amdgcn_mfma_f32_16x16x32_f16(a[kk], wf[kk], acc0, 0, 0, 0);
          acc1 = __builtin_amdgcn_mfma_f32_16x16x32_f16(ay[kk], wi[kk], acc1, 0, 0, 0);
        }
        acc0 = acc0 + acc1;

        const int gb = m * 16 + (lane >> 4) * 4;
        const int gc = n * 16 + (lane & 15);
#pragma unroll
        for (int r = 0; r < 4; ++r) gates_lds[(gb + r) * 36 + gc] = acc0[r];
        __syncthreads();

        const float gi = gates_lds[bb * 36 + 0 + jj] + bsum[0];
        const float gf = gates_lds[bb * 36 + 8 + jj] + bsum[1];
        const float gg = gates_lds[bb * 36 + 16 + jj] + bsum[2];
        const float go = gates_lds[bb * 36 + 24 + jj] + bsum[3];
        const float iv = sigmf(gi), fv = sigmf(gf), gv = tanhf_(gg), ov = sigmf(go);
        c_reg = fv * c_reg + iv * gv;
        const float hv = ov * tanhf_(c_reg);
        h_last = hv;
        st_h_agent(&g_y1[(size_t)s * BH + bb * H_ + j], hv);
        y1out[(size_t)(s - 1) * BH + bb * H_ + j] = hv;
      }
    }
    grid_barrier((unsigned)s + 2);
  }

  outh[layer * BH + bb * H_ + j] = h_last;
  outc[layer * BH + bb * H_ + j] = c_reg;
}

// ---------------------------------------------------------------------------
extern "C" void kernel_launch(void* const* d_in, const int* in_sizes, int n_in,
                              void* d_out, int out_size, void* d_ws, size_t ws_size,
                              hipStream_t stream) {
  (void)in_sizes; (void)n_in; (void)d_ws; (void)ws_size; (void)out_size;

  const int*   x    = (const int*)  d_in[0];
  const float* Hst  = (const float*)d_in[1];
  const float* Cst  = (const float*)d_in[2];
  const float* Wih0 = (const float*)d_in[3];
  const float* Whh0 = (const float*)d_in[4];
  const float* bih0 = (const float*)d_in[5];
  const float* bhh0 = (const float*)d_in[6];
  const float* Wih1 = (const float*)d_in[7];
  const float* Whh1 = (const float*)d_in[8];
  const float* bih1 = (const float*)d_in[9];
  const float* bhh1 = (const float*)d_in[10];

  float* out   = (float*)d_out;
  float* y1out = out;
  float* outh  = out + (size_t)T_ * BH;
  float* outc  = outh + (size_t)2 * BH;

  hipLaunchKernelGGL(init_bar_k, dim3(1), dim3(64), 0, stream);
  hipLaunchKernelGGL(transpose_wih0, dim3(8192), dim3(256), 0, stream, Wih0);
  hipLaunchKernelGGL(lstm_fused, dim3(GBLK), dim3(TPB), 0, stream,
                     Whh0, bih0, bhh0, Wih1, Whh1, bih1, bhh1,
                     x, Hst, Cst, y1out, outh, outc);
}

// Round 4
// 4208.404 us; speedup vs baseline: 1.5149x; 1.0633x over previous
//
#include <hip/hip_runtime.h>

#define DI __device__ __forceinline__

using half8 = __attribute__((ext_vector_type(8))) _Float16;
using f32x4 = __attribute__((ext_vector_type(4))) float;

static constexpr int T_ = 256;
static constexpr int B_ = 32;
static constexpr int H_ = 1024;
static constexpr int V_ = 8192;
static constexpr int GBLK = 256;
static constexpr int TPB = 256;
static constexpr int JPB = 8;
static constexpr int BH = B_ * H_;
static constexpr int NCTR = 16;    // arrival counters (16 blocks each)

__device__ _Float16 g_y0[(T_ + 1) * BH];
__device__ _Float16 g_y1[(T_ + 1) * BH];
__device__ _Float16 g_Wt[(size_t)V_ * 4096];  // W_ih0^T fp16: [vocab][4H]
__device__ unsigned g_cnt[NCTR * 32];         // 128B-strided
__device__ unsigned g_epoch;

__global__ void init_bar_k() {
  if (threadIdx.x < NCTR) g_cnt[threadIdx.x * 32] = 0u;
  if (threadIdx.x == 0) g_epoch = 0u;
}

// ---------------------------------------------------------------------------
// Prepass: W_ih0 (4096 x 8192) f32 -> g_Wt (8192 x 4096) fp16
// ---------------------------------------------------------------------------
__global__ __launch_bounds__(256) void transpose_wih0(const float* __restrict__ in) {
  __shared__ _Float16 t[64][72];
  const int bc = blockIdx.x & 127;
  const int br = blockIdx.x >> 7;
  const int r0 = br * 64, v0 = bc * 64;
  const int tx = threadIdx.x & 15, ty = threadIdx.x >> 4;
#pragma unroll
  for (int it = 0; it < 4; ++it) {
    const int row = ty + it * 16;
    const float4 f = *(const float4*)&in[(size_t)(r0 + row) * V_ + v0 + tx * 4];
    t[tx * 4 + 0][row] = (_Float16)f.x;
    t[tx * 4 + 1][row] = (_Float16)f.y;
    t[tx * 4 + 2][row] = (_Float16)f.z;
    t[tx * 4 + 3][row] = (_Float16)f.w;
  }
  __syncthreads();
#pragma unroll
  for (int it = 0; it < 4; ++it) {
    const int vrow = ty + it * 16;
    union { _Float16 h[4]; unsigned long long u; } o;
    o.h[0] = t[vrow][tx * 4 + 0]; o.h[1] = t[vrow][tx * 4 + 1];
    o.h[2] = t[vrow][tx * 4 + 2]; o.h[3] = t[vrow][tx * 4 + 3];
    *(unsigned long long*)&g_Wt[(size_t)(v0 + vrow) * 4096 + r0 + tx * 4] = o.u;
  }
}

// ---------------------------------------------------------------------------
DI half8 ld_h16_agent(const _Float16* p) {
  union { unsigned long long u[2]; half8 v; } r;
  r.u[0] = __hip_atomic_load((const unsigned long long*)p, __ATOMIC_RELAXED,
                             __HIP_MEMORY_SCOPE_AGENT);
  r.u[1] = __hip_atomic_load((const unsigned long long*)p + 1, __ATOMIC_RELAXED,
                             __HIP_MEMORY_SCOPE_AGENT);
  return r.v;
}

DI void st_h_agent(_Float16* p, float v) {
  const _Float16 h = (_Float16)v;
  __hip_atomic_store((short*)p, __builtin_bit_cast(short, h), __ATOMIC_RELAXED,
                     __HIP_MEMORY_SCOPE_AGENT);
}

// Master/epoch grid barrier: arrivals on 16 lines, only block 0 polls them,
// everyone else polls the single epoch line.
DI void grid_barrier(unsigned round) {
  __syncthreads();   // all waves drain vmem (h-stores at LLC) before arrival
  if (threadIdx.x == 0) {
    __hip_atomic_fetch_add(&g_cnt[(blockIdx.x & (NCTR - 1)) * 32], 1u,
                           __ATOMIC_RELAXED, __HIP_MEMORY_SCOPE_AGENT);
    if (blockIdx.x == 0) {
      const unsigned tgt = (GBLK / NCTR) * round;
      for (;;) {
        bool ok = true;
#pragma unroll
        for (int i = 0; i < NCTR; ++i)
          ok &= (__hip_atomic_load(&g_cnt[i * 32], __ATOMIC_RELAXED,
                                   __HIP_MEMORY_SCOPE_AGENT) >= tgt);
        if (ok) break;
        __builtin_amdgcn_s_sleep(1);
      }
      __hip_atomic_store(&g_epoch, round, __ATOMIC_RELAXED,
                         __HIP_MEMORY_SCOPE_AGENT);
    } else {
      while (__hip_atomic_load(&g_epoch, __ATOMIC_RELAXED,
                               __HIP_MEMORY_SCOPE_AGENT) < round)
        __builtin_amdgcn_s_sleep(1);
    }
  }
  __syncthreads();
}

DI float sigmf(float v) { return 1.0f / (1.0f + __expf(-v)); }
DI float tanhf_(float v) { return 1.0f - 2.0f / (__expf(2.0f * v) + 1.0f); }

DI half8 load8_cvt(const float* __restrict__ p) {
  const float4* q = (const float4*)p;
  float4 a = q[0], b = q[1];
  half8 r;
  r[0] = (_Float16)a.x; r[1] = (_Float16)a.y; r[2] = (_Float16)a.z; r[3] = (_Float16)a.w;
  r[4] = (_Float16)b.x; r[5] = (_Float16)b.y; r[6] = (_Float16)b.z; r[7] = (_Float16)b.w;
  return r;
}

// Fused 2-layer persistent LSTM. blocks 0-127: layer 0 (step s);
// blocks 128-255: layer 1 (step s-1).
__global__ __launch_bounds__(TPB, 1) void lstm_fused(
    const float* __restrict__ Whh0,
    const float* __restrict__ bih0, const float* __restrict__ bhh0,
    const float* __restrict__ Wih1,
    const float* __restrict__ Whh1,
    const float* __restrict__ bih1, const float* __restrict__ bhh1,
    const int* __restrict__ x,
    const float* __restrict__ Hst,
    const float* __restrict__ Cst,
    float* __restrict__ y1out,
    float* __restrict__ outh,
    float* __restrict__ outc)
{
  const int tid = threadIdx.x;
  const int bid = blockIdx.x;
  const int layer = bid >> 7;
  const int kb = bid & 127;
  const int jbase = kb * JPB;
  const int lane = tid & 63;
  const int w = tid >> 6;
  const int m = w & 1;
  const int n = w >> 1;
  const int bb = tid >> 3;
  const int jj = tid & 7;
  const int j = jbase + jj;

  __shared__ float gates_lds[32 * 36];
  __shared__ _Float16 wi_lds[32 * 1024];   // layer1: W_ih1 slice, XOR-swizzled

  const float* Whh = layer ? Whh1 : Whh0;
  const float* bih = layer ? bih1 : bih0;
  const float* bhh = layer ? bhh1 : bhh0;
  _Float16* mych = layer ? g_y1 : g_y0;

  st_h_agent(&mych[bb * H_ + j], Hst[layer * BH + bb * H_ + j]);
  float c_reg = Cst[layer * BH + bb * H_ + j];
  float bsum[4];
#pragma unroll
  for (int g = 0; g < 4; ++g) bsum[g] = bih[g * H_ + j] + bhh[g * H_ + j];

  // B-fragment geometry
  const int rowl = lane & 15;
  const int gW = n * 2 + (rowl >> 3);
  const int jW = rowl & 7;
  const int RW = gW * H_ + jbase + jW;
  const int kgrp = (lane >> 4) * 8;
  const int arow = m * 16 + (lane & 15);

  half8 wf[32];   // W_hh fragments, persistent in VGPRs
#pragma unroll
  for (int kk = 0; kk < 32; ++kk)
    wf[kk] = load8_cvt(Whh + (size_t)RW * H_ + kk * 32 + kgrp);

  // layer1: W_ih1 slice -> swizzled LDS (one-time)
  if (layer) {
    for (int idx = tid; idx < 32 * 128; idx += TPB) {
      const int row = idx >> 7;          // local gate row 0..31 (g*8+jw)
      const int ch = idx & 127;          // 16B chunk in row
      const int g = row >> 3, jw = row & 7;
      half8 v = load8_cvt(Wih1 + (size_t)(g * H_ + jbase + jw) * H_ + ch * 8);
      const unsigned byte = (unsigned)(row * 2048 + ch * 16) ^ (unsigned)((row & 15) << 4);
      *(half8*)((char*)wi_lds + byte) = v;
    }
    __syncthreads();
  }
  // B-read geometry for wi_lds: row = rowl16, chunk base = kgrp bytes*2
  const int rowl16 = n * 16 + (lane & 15);
  const unsigned bbase = (unsigned)(rowl16 * 2048 + (lane >> 4) * 16);
  const unsigned bxor = (unsigned)((rowl16 & 15) << 4);
  const char* wib = (const char*)wi_lds;

  grid_barrier(1);

  // layer0: prefetch gather for s=0
  float gx0 = 0.f, gx1 = 0.f, gx2 = 0.f, gx3 = 0.f;
  if (layer == 0) {
    const _Float16* gp = g_Wt + (size_t)x[bb] * 4096 + j;
    gx0 = (float)gp[0]; gx1 = (float)gp[1024];
    gx2 = (float)gp[2048]; gx3 = (float)gp[3072];
  }

  float h_last = 0.0f;
  for (int s = 0; s <= T_; ++s) {
    if (layer == 0) {
      if (s < T_) {
        const _Float16* hsrc = g_y0 + (size_t)s * BH + arow * H_ + kgrp;
        f32x4 acc0 = {0.f, 0.f, 0.f, 0.f}, acc1 = {0.f, 0.f, 0.f, 0.f};
        half8 a[32];
#pragma unroll
        for (int kk = 0; kk < 32; ++kk) a[kk] = ld_h16_agent(hsrc + kk * 32);
#pragma unroll
        for (int kk = 0; kk < 32; kk += 2) {
          acc0 = __builtin_amdgcn_mfma_f32_16x16x32_f16(a[kk], wf[kk], acc0, 0, 0, 0);
          acc1 = __builtin_amdgcn_mfma_f32_16x16x32_f16(a[kk + 1], wf[kk + 1], acc1, 0, 0, 0);
        }
        acc0 = acc0 + acc1;

        const int gb = m * 16 + (lane >> 4) * 4;
        const int gc = n * 16 + (lane & 15);
#pragma unroll
        for (int r = 0; r < 4; ++r) gates_lds[(gb + r) * 36 + gc] = acc0[r];
        __syncthreads();

        const float gi = gates_lds[bb * 36 + 0 + jj] + gx0 + bsum[0];
        const float gf = gates_lds[bb * 36 + 8 + jj] + gx1 + bsum[1];
        const float gg = gates_lds[bb * 36 + 16 + jj] + gx2 + bsum[2];
        const float go = gates_lds[bb * 36 + 24 + jj] + gx3 + bsum[3];
        const float iv = sigmf(gi), fv = sigmf(gf), gv = tanhf_(gg), ov = sigmf(go);
        c_reg = fv * c_reg + iv * gv;
        const float hv = ov * tanhf_(c_reg);
        h_last = hv;
        st_h_agent(&g_y0[(size_t)(s + 1) * BH + bb * H_ + j], hv);

        // prefetch next step's gather before the barrier (off critical path)
        if (s + 1 < T_) {
          const _Float16* gp = g_Wt + (size_t)x[(s + 1) * B_ + bb] * 4096 + j;
          gx0 = (float)gp[0]; gx1 = (float)gp[1024];
          gx2 = (float)gp[2048]; gx3 = (float)gp[3072];
        }
      }
    } else {
      if (s >= 1) {
        const _Float16* hsrc = g_y1 + (size_t)(s - 1) * BH + arow * H_ + kgrp;
        const _Float16* ysrc = g_y0 + (size_t)s * BH + arow * H_ + kgrp;
        f32x4 acc0 = {0.f, 0.f, 0.f, 0.f}, acc1 = {0.f, 0.f, 0.f, 0.f};
        half8 a[32], ay[32];
#pragma unroll
        for (int kk = 0; kk < 32; ++kk) a[kk] = ld_h16_agent(hsrc + kk * 32);
#pragma unroll
        for (int kk = 0; kk < 32; ++kk) ay[kk] = ld_h16_agent(ysrc + kk * 32);
#pragma unroll
        for (int kk = 0; kk < 32; ++kk) {
          acc0 = __builtin_amdgcn_mfma_f32_16x16x32_f16(a[kk], wf[kk], acc0, 0, 0, 0);
          const half8 bi = *(const half8*)(wib + ((bbase + (unsigned)(kk * 64)) ^ bxor));
          acc1 = __builtin_amdgcn_mfma_f32_16x16x32_f16(ay[kk], bi, acc1, 0, 0, 0);
        }
        acc0 = acc0 + acc1;

        const int gb = m * 16 + (lane >> 4) * 4;
        const int gc = n * 16 + (lane & 15);
#pragma unroll
        for (int r = 0; r < 4; ++r) gates_lds[(gb + r) * 36 + gc] = acc0[r];
        __syncthreads();

        const float gi = gates_lds[bb * 36 + 0 + jj] + bsum[0];
        const float gf = gates_lds[bb * 36 + 8 + jj] + bsum[1];
        const float gg = gates_lds[bb * 36 + 16 + jj] + bsum[2];
        const float go = gates_lds[bb * 36 + 24 + jj] + bsum[3];
        const float iv = sigmf(gi), fv = sigmf(gf), gv = tanhf_(gg), ov = sigmf(go);
        c_reg = fv * c_reg + iv * gv;
        const float hv = ov * tanhf_(c_reg);
        h_last = hv;
        st_h_agent(&g_y1[(size_t)s * BH + bb * H_ + j], hv);
        y1out[(size_t)(s - 1) * BH + bb * H_ + j] = hv;
      }
    }
    grid_barrier((unsigned)s + 2);
  }

  outh[layer * BH + bb * H_ + j] = h_last;
  outc[layer * BH + bb * H_ + j] = c_reg;
}

// ---------------------------------------------------------------------------
extern "C" void kernel_launch(void* const* d_in, const int* in_sizes, int n_in,
                              void* d_out, int out_size, void* d_ws, size_t ws_size,
                              hipStream_t stream) {
  (void)in_sizes; (void)n_in; (void)d_ws; (void)ws_size; (void)out_size;

  const int*   x    = (const int*)  d_in[0];
  const float* Hst  = (const float*)d_in[1];
  const float* Cst  = (const float*)d_in[2];
  const float* Wih0 = (const float*)d_in[3];
  const float* Whh0 = (const float*)d_in[4];
  const float* bih0 = (const float*)d_in[5];
  const float* bhh0 = (const float*)d_in[6];
  const float* Wih1 = (const float*)d_in[7];
  const float* Whh1 = (const float*)d_in[8];
  const float* bih1 = (const float*)d_in[9];
  const float* bhh1 = (const float*)d_in[10];

  float* out   = (float*)d_out;
  float* y1out = out;
  float* outh  = out + (size_t)T_ * BH;
  float* outc  = outh + (size_t)2 * BH;

  hipLaunchKernelGGL(init_bar_k, dim3(1), dim3(64), 0, stream);
  hipLaunchKernelGGL(transpose_wih0, dim3(8192), dim3(256), 0, stream, Wih0);
  hipLaunchKernelGGL(lstm_fused, dim3(GBLK), dim3(TPB), 0, stream,
                     Whh0, bih0, bhh0, Wih1, Whh1, bih1, bhh1,
                     x, Hst, Cst, y1out, outh, outc);
}